// Round 9
// baseline (452.956 us; speedup 1.0000x reference)
//
#include <hip/hip_runtime.h>
#include <math.h>

// MultiheadAttentionQ: W8A8 fake-quant MHA. S=2048, B=2, D=1024, H=16, hd=64.
// R9 = R8 with builtin-name fix (mfma_f32_16x16x16f16 — no underscore).
// attn LDS-traffic redesign: S^T via swapped MFMA operands -> S^T C-layout IS
// the A-layout of mfma_16x16x16 -> P stays in registers. 128-row q-tiles.
// V quad-major-permuted globally so PV B-frags are contiguous b128 from LDS.

typedef _Float16 f16;
typedef _Float16 half8 __attribute__((ext_vector_type(8)));
typedef _Float16 half4 __attribute__((ext_vector_type(4)));
typedef _Float16 half2v __attribute__((ext_vector_type(2)));
typedef __fp16 fp16x2 __attribute__((ext_vector_type(2)));
typedef float floatx4 __attribute__((ext_vector_type(4)));
typedef int int4v __attribute__((ext_vector_type(4)));

#define QMAX 127.0f

#define SLOT_WI 0
#define SLOT_WO 1
#define SLOT_XQ 2
#define SLOT_XK 3
#define SLOT_XV 4
#define SLOT_HD 5
#define SLOT_Y  6
#define SLOT_Q  7

__device__ __forceinline__ float slot_scale(const unsigned* slots, int slot, float premul) {
  if (slot < 0) return 1.0f;
  return fmaxf(__uint_as_float(slots[slot]) * premul / QMAX, 1e-8f);
}

__device__ __forceinline__ void gl2lds16(const void* gsrc, void* ldst) {
  __builtin_amdgcn_global_load_lds((__attribute__((address_space(1))) void*)gsrc,
                                   (__attribute__((address_space(3))) void*)ldst, 16, 0, 0);
}

__device__ __forceinline__ half2v pack2(float a, float b) {
  fp16x2 r = __builtin_amdgcn_cvt_pkrtz(a, b);
  return __builtin_bit_cast(half2v, r);
}

__global__ __launch_bounds__(64) void init_slots_k(unsigned* slots) {
  if (threadIdx.x < 16) slots[threadIdx.x] = 0u;
}

// Fused absmax of Wi (blocks < 768) and Wo (blocks >= 768).
__global__ __launch_bounds__(256) void absmax2_k(const float* __restrict__ Wi,
                                                 const float* __restrict__ Wo,
                                                 unsigned* __restrict__ slots) {
  __shared__ float red[256];
  int tid = threadIdx.x;
  const float4* x4;
  int n4, i0, stride, slot;
  if (blockIdx.x < 768) {
    x4 = (const float4*)Wi; n4 = 786432; i0 = blockIdx.x * 256 + tid;
    stride = 768 * 256; slot = SLOT_WI;
  } else {
    x4 = (const float4*)Wo; n4 = 262144; i0 = (blockIdx.x - 768) * 256 + tid;
    stride = 256 * 256; slot = SLOT_WO;
  }
  float lmax = 0.f;
  for (int i = i0; i < n4; i += stride) {
    float4 v = x4[i];
    lmax = fmaxf(lmax, fmaxf(fmaxf(fabsf(v.x), fabsf(v.y)), fmaxf(fabsf(v.z), fabsf(v.w))));
  }
  red[tid] = lmax; __syncthreads();
  for (int sh = 128; sh > 0; sh >>= 1) {
    if (tid < sh) red[tid] = fmaxf(red[tid], red[tid + sh]);
    __syncthreads();
  }
  if (tid == 0) atomicMax(&slots[slot], __float_as_uint(red[0]));
}

// Fused weight quant: Wi -> f16 codes (blocks < 768), Wo -> i8 codes.
__global__ __launch_bounds__(256) void quantw_k(const float* __restrict__ Wi,
                                                const float* __restrict__ Wo,
                                                f16* __restrict__ Wiq,
                                                char* __restrict__ Wo8,
                                                const unsigned* __restrict__ slots) {
  int tid = threadIdx.x;
  if (blockIdx.x < 768) {
    float s = slot_scale(slots, SLOT_WI, 1.0f);
    const float4* in4 = (const float4*)Wi;
    for (int i = blockIdx.x * 256 + tid; i < 786432; i += 768 * 256) {
      float4 v = in4[i];
      float xs[4] = {v.x, v.y, v.z, v.w};
      half4 o;
#pragma unroll
      for (int u = 0; u < 4; ++u) {
        float r = rintf(xs[u] / s);
        o[u] = (f16)fminf(fmaxf(r, -128.0f), 127.0f);
      }
      *(half4*)(Wiq + (size_t)i * 4) = o;
    }
  } else {
    float s = slot_scale(slots, SLOT_WO, 1.0f);
    const float4* in4 = (const float4*)Wo;
    for (int i = (blockIdx.x - 768) * 256 + tid; i < 262144; i += 256 * 256) {
      float4 v = in4[i];
      char4 o;
      o.x = (signed char)(int)fminf(fmaxf(rintf(v.x / s), -128.0f), 127.0f);
      o.y = (signed char)(int)fminf(fmaxf(rintf(v.y / s), -128.0f), 127.0f);
      o.z = (signed char)(int)fminf(fmaxf(rintf(v.z / s), -128.0f), 127.0f);
      o.w = (signed char)(int)fminf(fmaxf(rintf(v.w / s), -128.0f), 127.0f);
      *(char4*)(Wo8 + (size_t)i * 4) = o;
    }
  }
}

// fp32 -> fp32 fake-quant (n*s).
__global__ __launch_bounds__(256) void quantf_k(const float* __restrict__ in, float* __restrict__ out,
                                                int n4, unsigned* __restrict__ slots,
                                                int sSlot, float premul) {
  float s = slot_scale(slots, sSlot, premul);
  const float4* in4 = (const float4*)in;
  float4* out4 = (float4*)out;
  for (int i = blockIdx.x * 256 + threadIdx.x; i < n4; i += gridDim.x * 256) {
    float4 v = in4[i];
    float xs[4] = {v.x, v.y, v.z, v.w};
#pragma unroll
    for (int u = 0; u < 4; ++u) {
      float r = rintf((xs[u] * premul) / s);
      r = fminf(fmaxf(r, -128.0f), 127.0f);
      xs[u] = r * s;
    }
    out4[i] = make_float4(xs[0], xs[1], xs[2], xs[3]);
  }
}

// fp32 -> f16 integer codes. Optionally records absmax of quantized value.
__global__ __launch_bounds__(256) void quanti_k(const float* __restrict__ in, f16* __restrict__ out,
                                                int n4, unsigned* __restrict__ slots,
                                                int sSlot, int outAbsSlot) {
  __shared__ float red[256];
  float s = slot_scale(slots, sSlot, 1.0f);
  float lmax = 0.f;
  const float4* in4 = (const float4*)in;
  for (int i = blockIdx.x * 256 + threadIdx.x; i < n4; i += gridDim.x * 256) {
    float4 v = in4[i];
    float xs[4] = {v.x, v.y, v.z, v.w};
    half4 o;
#pragma unroll
    for (int u = 0; u < 4; ++u) {
      float r = rintf(xs[u] / s);
      r = fminf(fmaxf(r, -128.0f), 127.0f);
      o[u] = (f16)r;
      lmax = fmaxf(lmax, fabsf(r));
    }
    *(half4*)(out + (size_t)i * 4) = o;
  }
  if (outAbsSlot >= 0) {
    int tid = threadIdx.x;
    red[tid] = lmax; __syncthreads();
    for (int sh = 128; sh > 0; sh >>= 1) {
      if (tid < sh) red[tid] = fmaxf(red[tid], red[tid + sh]);
      __syncthreads();
    }
    if (tid == 0) atomicMax(&slots[outAbsSlot], __float_as_uint(red[0] * s));
  }
}

// fp32 -> i8 codes (for Hd -> Hint8).
__global__ __launch_bounds__(256) void quant8_k(const float* __restrict__ in, char* __restrict__ out,
                                                int n4, const unsigned* __restrict__ slots,
                                                int sSlot) {
  float s = slot_scale(slots, sSlot, 1.0f);
  const float4* in4 = (const float4*)in;
  for (int i = blockIdx.x * 256 + threadIdx.x; i < n4; i += gridDim.x * 256) {
    float4 v = in4[i];
    char4 o;
    o.x = (signed char)(int)fminf(fmaxf(rintf(v.x / s), -128.0f), 127.0f);
    o.y = (signed char)(int)fminf(fmaxf(rintf(v.y / s), -128.0f), 127.0f);
    o.z = (signed char)(int)fminf(fmaxf(rintf(v.z / s), -128.0f), 127.0f);
    o.w = (signed char)(int)fminf(fmaxf(rintf(v.w / s), -128.0f), 127.0f);
    *(char4*)(out + (size_t)i * 4) = o;
  }
}

// fp32 -> hi/lo f16 split.
__global__ __launch_bounds__(256) void split_k(const float* __restrict__ in,
                                               f16* __restrict__ hi, f16* __restrict__ lo, int n4) {
  const float4* in4 = (const float4*)in;
  for (int i = blockIdx.x * 256 + threadIdx.x; i < n4; i += gridDim.x * 256) {
    float4 v = in4[i];
    float xs[4] = {v.x, v.y, v.z, v.w};
    half4 h, l;
#pragma unroll
    for (int u = 0; u < 4; ++u) {
      f16 hv = (f16)xs[u];
      h[u] = hv;
      l[u] = (f16)(xs[u] - (float)hv);
    }
    *(half4*)(hi + (size_t)i * 4) = h;
    *(half4*)(lo + (size_t)i * 4) = l;
  }
}

// Fused V: quantize Xv -> codes, transpose per head, quad-major k-permute
// within each 64-k tile: pos = q4*16 + t*4 + j  <-  k = t*16 + q4*4 + j.
__global__ __launch_bounds__(256) void quantv_t_k(const float* __restrict__ Xv,
                                                  f16* __restrict__ Vt,
                                                  const unsigned* __restrict__ slots) {
  __shared__ f16 T[64][68];
  int tid = threadIdx.x;
  int bh = blockIdx.y, b = bh >> 4, h = bh & 15;
  int k0 = blockIdx.x * 64;
  float s = slot_scale(slots, SLOT_XV, 1.0f);
#pragma unroll
  for (int it = 0; it < 4; ++it) {
    int idx = tid + it * 256;
    int row = idx >> 4, dseg = idx & 15;
    float4 v = *(const float4*)(Xv + ((size_t)(k0 + row) * 2 + b) * 1024 + h * 64 + dseg * 4);
    float xs[4] = {v.x, v.y, v.z, v.w};
    half4 o;
#pragma unroll
    for (int u = 0; u < 4; ++u) {
      float r = rintf(xs[u] / s);
      o[u] = (f16)fminf(fmaxf(r, -128.0f), 127.0f);
    }
    *(half4*)&T[row][dseg * 4] = o;
  }
  __syncthreads();
#pragma unroll
  for (int it = 0; it < 2; ++it) {
    int sdx = tid + it * 256;
    int d = sdx >> 3, j = sdx & 7;
    half8 o;
#pragma unroll
    for (int l = 0; l < 8; ++l) {
      int pos = j * 8 + l;
      int k = ((pos >> 2) & 3) * 16 + (pos >> 4) * 4 + (pos & 3);
      o[l] = T[k][d];
    }
    *(half8*)(Vt + ((size_t)bh * 64 + d) * 2048 + k0 + j * 8) = o;
  }
}

// f16 MFMA GEMM, BK=32 (R5/R7 structure). C = (A0+A1) @ B^T * sB + bias.
__global__ __launch_bounds__(256) void gemm_mfma_k(const f16* __restrict__ A0,
                                                   const f16* __restrict__ A1,
                                                   const f16* __restrict__ B,
                                                   const float* __restrict__ bias,
                                                   float* __restrict__ out,
                                                   unsigned* __restrict__ slots,
                                                   int slotB, int absSlot,
                                                   int K, int colLo, int colCount) {
  __shared__ f16 AsH[128 * 32];
  __shared__ f16 Bs[128 * 32];
  __shared__ f16 AsL[128 * 32];
  __shared__ float red[256];

  int tid = threadIdx.x;
  int lane = tid & 63, w = tid >> 6;
  int wm = w >> 1, wn = w & 1;
  int quad = lane >> 4, l15 = lane & 15;
  int m0 = blockIdx.y * 128, n0 = blockIdx.x * 128;

  int srow = lane >> 2;
  int sgr = (lane & 3) * 8;

  floatx4 acc[4][4];
#pragma unroll
  for (int i = 0; i < 4; ++i)
#pragma unroll
    for (int j = 0; j < 4; ++j) acc[i][j] = (floatx4){0.f, 0.f, 0.f, 0.f};

  for (int k0 = 0; k0 < K; k0 += 32) {
    __syncthreads();
#pragma unroll
    for (int t = 0; t < 2; ++t) {
      int r0 = (w * 2 + t) * 16;
      gl2lds16(A0 + (size_t)(m0 + r0 + srow) * K + k0 + sgr, &AsH[r0 * 32]);
      gl2lds16(B + (size_t)(n0 + r0 + srow) * K + k0 + sgr, &Bs[r0 * 32]);
      gl2lds16(A1 + (size_t)(m0 + r0 + srow) * K + k0 + sgr, &AsL[r0 * 32]);
    }
    __syncthreads();
    half8 ah[4], bfr[4], al[4];
#pragma unroll
    for (int i = 0; i < 4; ++i) ah[i] = *(half8*)&AsH[(wm * 64 + i * 16 + l15) * 32 + quad * 8];
#pragma unroll
    for (int j = 0; j < 4; ++j) bfr[j] = *(half8*)&Bs[(wn * 64 + j * 16 + l15) * 32 + quad * 8];
#pragma unroll
    for (int i = 0; i < 4; ++i) al[i] = *(half8*)&AsL[(wm * 64 + i * 16 + l15) * 32 + quad * 8];
#pragma unroll
    for (int i = 0; i < 4; ++i)
#pragma unroll
      for (int j = 0; j < 4; ++j) {
        acc[i][j] = __builtin_amdgcn_mfma_f32_16x16x32_f16(ah[i], bfr[j], acc[i][j], 0, 0, 0);
        acc[i][j] = __builtin_amdgcn_mfma_f32_16x16x32_f16(al[i], bfr[j], acc[i][j], 0, 0, 0);
      }
  }

  float sc = slot_scale(slots, slotB, 1.0f);
  float lmax = 0.f;
#pragma unroll
  for (int i = 0; i < 4; ++i) {
#pragma unroll
    for (int j = 0; j < 4; ++j) {
      int gn = n0 + wn * 64 + j * 16 + l15;
      float bv = bias[gn];
#pragma unroll
      for (int r = 0; r < 4; ++r) {
        int gm = m0 + wm * 64 + i * 16 + quad * 4 + r;
        float v = acc[i][j][r] * sc + bv;
        lmax = fmaxf(lmax, fabsf(v));
        if (gn >= colLo && gn < colLo + colCount)
          out[(size_t)gm * colCount + (gn - colLo)] = v;
      }
    }
  }
  red[tid] = lmax; __syncthreads();
  for (int sh = 128; sh > 0; sh >>= 1) {
    if (tid < sh) red[tid] = fmaxf(red[tid], red[tid + sh]);
    __syncthreads();
  }
  if (tid == 0) atomicMax(&slots[absSlot], __float_as_uint(red[0]));
}

// Exact i8 output GEMM: Y = (Hint8 @ Wo8^T) * (sH*sW) + bo.
__global__ __launch_bounds__(256) void gemm_i8out_k(const char* __restrict__ A8,
                                                    const char* __restrict__ B8,
                                                    const float* __restrict__ bias,
                                                    float* __restrict__ out,
                                                    unsigned* __restrict__ slots) {
  __shared__ char As8[128 * 64];
  __shared__ char Bs8[128 * 64];
  __shared__ float red[256];

  const int K = 1024;
  int tid = threadIdx.x;
  int lane = tid & 63, w = tid >> 6;
  int wm = w >> 1, wn = w & 1;
  int quad = lane >> 4, l15 = lane & 15;
  int m0 = blockIdx.y * 128, n0 = blockIdx.x * 128;

  int srow = lane >> 2;
  int sgr = (lane & 3) * 16;

  int4v acc[4][4];
#pragma unroll
  for (int i = 0; i < 4; ++i)
#pragma unroll
    for (int j = 0; j < 4; ++j) acc[i][j] = (int4v){0, 0, 0, 0};

  for (int k0 = 0; k0 < K; k0 += 64) {
    __syncthreads();
#pragma unroll
    for (int t = 0; t < 2; ++t) {
      int r0 = (w * 2 + t) * 16;
      int row = r0 + srow;
      gl2lds16(A8 + (size_t)(m0 + row) * K + k0 + sgr, &As8[r0 * 64]);
      gl2lds16(B8 + (size_t)(n0 + row) * K + k0 + sgr, &Bs8[r0 * 64]);
    }
    __syncthreads();
    int4v af[4], bf[4];
#pragma unroll
    for (int i = 0; i < 4; ++i)
      af[i] = *(const int4v*)&As8[(wm * 64 + i * 16 + l15) * 64 + quad * 16];
#pragma unroll
    for (int j = 0; j < 4; ++j)
      bf[j] = *(const int4v*)&Bs8[(wn * 64 + j * 16 + l15) * 64 + quad * 16];
#pragma unroll
    for (int i = 0; i < 4; ++i)
#pragma unroll
      for (int j = 0; j < 4; ++j)
        acc[i][j] = __builtin_amdgcn_mfma_i32_16x16x64_i8(af[i], bf[j], acc[i][j], 0, 0, 0);
  }

  float sc = slot_scale(slots, SLOT_HD, 1.0f) * slot_scale(slots, SLOT_WO, 1.0f);
  float lmax = 0.f;
#pragma unroll
  for (int i = 0; i < 4; ++i) {
#pragma unroll
    for (int j = 0; j < 4; ++j) {
      int gn = n0 + wn * 64 + j * 16 + l15;
      float bv = bias[gn];
#pragma unroll
      for (int r = 0; r < 4; ++r) {
        int gm = m0 + wm * 64 + i * 16 + quad * 4 + r;
        float v = (float)acc[i][j][r] * sc + bv;
        lmax = fmaxf(lmax, fabsf(v));
        out[(size_t)gm * 1024 + gn] = v;
      }
    }
  }
  red[tid] = lmax; __syncthreads();
  for (int sh = 128; sh > 0; sh >>= 1) {
    if (tid < sh) red[tid] = fmaxf(red[tid], red[tid + sh]);
    __syncthreads();
  }
  if (tid == 0) atomicMax(&slots[SLOT_Y], __float_as_uint(red[0]));
}

// Flash attention R9. 128 q-rows/block; each wave owns 32 q-rows (2x16 subs).
// S^T = K·Q^T via mfma(kf, qf): C-layout lane l15 = q, reg r -> k = quad*4+r,
// which IS the A-operand layout of mfma_f32_16x16x16f16 -> P stays in regs.
// PV B-frag: V quad-major-permuted [d][pos], staged to padded LDS via VGPR.
// Fixed-offset softmax (no max bookkeeping); l reduced across quads at end.
__global__ __launch_bounds__(256) void attn_k(const f16* __restrict__ Qc,
                                              const f16* __restrict__ Kh,
                                              const f16* __restrict__ Vt,
                                              float* __restrict__ heads,
                                              unsigned* __restrict__ slots) {
  __shared__ f16 Ks[64 * 64];
  __shared__ f16 Vs[64][72];
  __shared__ float lred[4][2][16];
  __shared__ float red[256];

  int tid = threadIdx.x;
  int lane = tid & 63, w = tid >> 6;
  int quad = lane >> 4, l15 = lane & 15;
  int bh = blockIdx.y, b = bh >> 4, h = bh & 15;
  int q0 = blockIdx.x * 128;

  float s1 = slot_scale(slots, SLOT_XQ, 1.0f);
  float sq = slot_scale(slots, SLOT_Q, 0.125f);
  float sk = slot_scale(slots, SLOT_XK, 1.0f);
  float sv = slot_scale(slots, SLOT_XV, 1.0f);
  float cS = sq * sk * 1.44269504088896340736f;
  const float FOFF = 12.0f;  // cancels in P/l

  // Q fragments for both sub-tiles, remap fake_quant(Q/8) inline
  half8 qf[2][2];
#pragma unroll
  for (int s = 0; s < 2; ++s) {
    const f16* qrow = Qc + ((size_t)(q0 + w * 32 + s * 16 + l15) * 2 + b) * 1024 + h * 64;
    half8 qr0 = *(const half8*)(qrow + quad * 8);
    half8 qr1 = *(const half8*)(qrow + 32 + quad * 8);
#pragma unroll
    for (int u = 0; u < 8; ++u) {
      float x0 = ((float)qr0[u] * s1) * 0.125f;
      float x1 = ((float)qr1[u] * s1) * 0.125f;
      qf[s][0][u] = (f16)fminf(fmaxf(rintf(x0 / sq), -128.0f), 127.0f);
      qf[s][1][u] = (f16)fminf(fmaxf(rintf(x1 / sq), -128.0f), 127.0f);
    }
  }

  int ksrow = lane >> 3;  // K staging row-within-8
  int ksp = lane & 7;     // K staging granule
  int vr0 = tid >> 3, vs0 = (tid & 7) * 8;  // V staging (2 half8/thread)

  floatx4 oacc[2][4];
#pragma unroll
  for (int s = 0; s < 2; ++s)
#pragma unroll
    for (int d = 0; d < 4; ++d) oacc[s][d] = (floatx4){0.f, 0.f, 0.f, 0.f};
  float lsum[2] = {0.f, 0.f};

  const f16* vbase = Vt + (size_t)bh * 131072;  // bh*64*2048

  for (int kt = 0; kt < 2048; kt += 64) {
    __syncthreads();
    // K: async global->LDS (swizzled granules, as R7)
#pragma unroll
    for (int t = 0; t < 2; ++t) {
      int r0 = (w * 2 + t) * 8;
      int row = r0 + ksrow;
      int g = ksp ^ (row & 7);
      gl2lds16(Kh + ((size_t)(kt + row) * 2 + b) * 1024 + h * 64 + g * 8, &Ks[r0 * 64]);
    }
    // V: VGPR staging into padded rows (pos-space already permuted globally)
    half8 va = *(const half8*)(vbase + (size_t)vr0 * 2048 + kt + vs0);
    half8 vb = *(const half8*)(vbase + (size_t)(vr0 + 32) * 2048 + kt + vs0);
    *(half8*)&Vs[vr0][vs0] = va;
    *(half8*)&Vs[vr0 + 32][vs0] = vb;
    __syncthreads();

    // S^T (per k-block t), softmax, P fragments in registers
    half4 aph[2][4], apl[2][4];
#pragma unroll
    for (int t = 0; t < 4; ++t) {
      int row = t * 16 + l15;
      int g1 = quad ^ (row & 7);
      half8 kf0 = *(half8*)&Ks[row * 64 + g1 * 8];
      half8 kf1 = *(half8*)&Ks[row * 64 + (g1 ^ 4) * 8];
#pragma unroll
      for (int s = 0; s < 2; ++s) {
        floatx4 sacc = (floatx4){0.f, 0.f, 0.f, 0.f};
        sacc = __builtin_amdgcn_mfma_f32_16x16x32_f16(kf0, qf[s][0], sacc, 0, 0, 0);
        sacc = __builtin_amdgcn_mfma_f32_16x16x32_f16(kf1, qf[s][1], sacc, 0, 0, 0);
        float p0 = __builtin_amdgcn_exp2f(fmaf(sacc[0], cS, -FOFF));
        float p1 = __builtin_amdgcn_exp2f(fmaf(sacc[1], cS, -FOFF));
        float p2 = __builtin_amdgcn_exp2f(fmaf(sacc[2], cS, -FOFF));
        float p3 = __builtin_amdgcn_exp2f(fmaf(sacc[3], cS, -FOFF));
        lsum[s] += (p0 + p1) + (p2 + p3);
        half2v h01 = pack2(p0, p1);
        half2v h23 = pack2(p2, p3);
        half2v l01 = pack2(p0 - (float)h01[0], p1 - (float)h01[1]);
        half2v l23 = pack2(p2 - (float)h23[0], p3 - (float)h23[1]);
        aph[s][t][0] = h01[0]; aph[s][t][1] = h01[1];
        aph[s][t][2] = h23[0]; aph[s][t][3] = h23[1];
        apl[s][t][0] = l01[0]; apl[s][t][1] = l01[1];
        apl[s][t][2] = l23[0]; apl[s][t][3] = l23[1];
      }
    }

    // PV: O[q][d] += P·V, k=16 MFMAs; B-frags = 2 contiguous b128 per d-block
#pragma unroll
    for (int d = 0; d < 4; ++d) {
      const f16* vsrow = &Vs[d * 16 + l15][quad * 16];
      half8 b0 = *(const half8*)vsrow;
      half8 b1 = *(const half8*)(vsrow + 8);
      half4 bf[4];
#pragma unroll
      for (int u = 0; u < 4; ++u) {
        bf[0][u] = b0[u]; bf[1][u] = b0[u + 4];
        bf[2][u] = b1[u]; bf[3][u] = b1[u + 4];
      }
#pragma unroll
      for (int t = 0; t < 4; ++t)
#pragma unroll
        for (int s = 0; s < 2; ++s) {
          oacc[s][d] = __builtin_amdgcn_mfma_f32_16x16x16f16(aph[s][t], bf[t], oacc[s][d], 0, 0, 0);
          oacc[s][d] = __builtin_amdgcn_mfma_f32_16x16x16f16(apl[s][t], bf[t], oacc[s][d], 0, 0, 0);
        }
    }
  }

  // l: reduce across the 4 quads (lanes l15, +16, +32, +48), broadcast via LDS
#pragma unroll
  for (int s = 0; s < 2; ++s) {
    float l = lsum[s];
    l += __shfl_xor(l, 16);
    l += __shfl_xor(l, 32);
    lred[w][s][l15] = l;
  }
  // own-wave LDS round-trip (lgkmcnt orders it)
  float linv[2][4];
#pragma unroll
  for (int s = 0; s < 2; ++s)
#pragma unroll
    for (int r = 0; r < 4; ++r) linv[s][r] = sv / lred[w][s][quad * 4 + r];

  float lmax = 0.f;
#pragma unroll
  for (int s = 0; s < 2; ++s)
#pragma unroll
    for (int d = 0; d < 4; ++d)
#pragma unroll
      for (int r = 0; r < 4; ++r) {
        float hv = oacc[s][d][r] * linv[s][r];
        heads[((size_t)(q0 + w * 32 + s * 16 + quad * 4 + r) * 2 + b) * 1024 +
              h * 64 + d * 16 + l15] = hv;
        lmax = fmaxf(lmax, fabsf(hv));
      }
  red[tid] = lmax; __syncthreads();
  for (int sh = 128; sh > 0; sh >>= 1) {
    if (tid < sh) red[tid] = fmaxf(red[tid], red[tid + sh]);
    __syncthreads();
  }
  if (tid == 0) atomicMax(&slots[SLOT_HD], __float_as_uint(red[0]));
}

extern "C" void kernel_launch(void* const* d_in, const int* in_sizes, int n_in,
                              void* d_out, int out_size, void* d_ws, size_t ws_size,
                              hipStream_t stream) {
  (void)in_sizes; (void)n_in; (void)out_size; (void)ws_size;
  const float* query = (const float*)d_in[0];
  const float* key   = (const float*)d_in[1];
  const float* value = (const float*)d_in[2];
  const float* Wi    = (const float*)d_in[3];
  const float* bi    = (const float*)d_in[4];
  const float* Wo    = (const float*)d_in[5];
  const float* bo    = (const float*)d_in[6];
  float* out = (float*)d_out;

  char* p = (char*)d_ws;
  unsigned* slots = (unsigned*)p;            p += 1024;
  f16* Wiq  = (f16*)p;                       p += 3072 * 1024 * 2;
  char* Wo8 = (char*)p;                      p += 1024 * 1024;
  f16* Ahi  = (f16*)p;                       p += 4096 * 1024 * 2;
  f16* Alo  = (f16*)p;                       p += 4096 * 1024 * 2;
  float* Hd = (float*)Ahi;                   // alias (spans Ahi+Alo), after GEMM3
  float* Xq = (float*)p;                     p += 4096 * 1024 * 4;
  float* Y  = Xq;                            // alias: Xq dead after Qc made
  float* Xk = (float*)p;                     p += 4096 * 1024 * 4;
  f16* Qc   = (f16*)Xk;                      // alias: Xk dead after Kint (sequential)
  float* Xv = (float*)p;                     p += 4096 * 1024 * 4;
  char* Hint8 = (char*)Xv + 4096 * 1024 * 2; // alias: Xv dead after quantv_t
  f16* Kint = (f16*)p;                       p += 4096 * 1024 * 2;
  f16* Vt   = (f16*)p;                       p += 4096 * 1024 * 2;

  init_slots_k<<<1, 64, 0, stream>>>(slots);
  absmax2_k<<<1024, 256, 0, stream>>>(Wi, Wo, slots);
  quantw_k<<<1024, 256, 0, stream>>>(Wi, Wo, Wiq, Wo8, slots);

  dim3 g1(24, 32);  // N=3072, M=4096
  split_k<<<1024, 256, 0, stream>>>(query, Ahi, Alo, 1048576);
  gemm_mfma_k<<<g1, 256, 0, stream>>>(Ahi, Alo, Wiq, bi, Xq, slots, SLOT_WI, SLOT_XQ,
                                      1024, 0, 1024);
  split_k<<<1024, 256, 0, stream>>>(key, Ahi, Alo, 1048576);
  gemm_mfma_k<<<g1, 256, 0, stream>>>(Ahi, Alo, Wiq, bi, Xk, slots, SLOT_WI, SLOT_XK,
                                      1024, 1024, 1024);
  split_k<<<1024, 256, 0, stream>>>(value, Ahi, Alo, 1048576);
  gemm_mfma_k<<<g1, 256, 0, stream>>>(Ahi, Alo, Wiq, bi, Xv, slots, SLOT_WI, SLOT_XV,
                                      1024, 2048, 1024);

  quanti_k<<<1024, 256, 0, stream>>>(Xk, Kint, 1048576, slots, SLOT_XK, -1);
  quanti_k<<<1024, 256, 0, stream>>>(Xq, Qc, 1048576, slots, SLOT_XQ, SLOT_Q);

  dim3 gvt(32, 32);
  quantv_t_k<<<gvt, 256, 0, stream>>>(Xv, Vt, slots);

  dim3 ga(16, 32);
  attn_k<<<ga, 256, 0, stream>>>(Qc, Kint, Vt, Hd, slots);

  quant8_k<<<1024, 256, 0, stream>>>(Hd, Hint8, 1048576, slots, SLOT_HD);

  dim3 g2(8, 32);  // N=1024, M=4096
  gemm_i8out_k<<<g2, 256, 0, stream>>>(Hint8, Wo8, bo, Y, slots);

  quantf_k<<<1024, 256, 0, stream>>>(Y, out, 1048576, slots, SLOT_Y, 1.0f);
}

// Round 10
// 443.895 us; speedup vs baseline: 1.0204x; 1.0204x over previous
//
#include <hip/hip_runtime.h>
#include <math.h>

// MultiheadAttentionQ: W8A8 fake-quant MHA. S=2048, B=2, D=1024, H=16, hd=64.
// R10: R9's P-in-registers attn, but PV back on K=32 MFMA: two 16-k S^T blocks
// fused into one 16x16x32 A-fragment (j<4 <- t even regs, j>=4 <- t odd regs),
// V global permutation adjusted to match (k = tp*32 + q*4 + (j<4? j : j+12)).
// R9's 16x16x16f16 PV ran at half rate (same cycles, half FLOPs) — that was
// the R9 regression.

typedef _Float16 f16;
typedef _Float16 half8 __attribute__((ext_vector_type(8)));
typedef _Float16 half4 __attribute__((ext_vector_type(4)));
typedef _Float16 half2v __attribute__((ext_vector_type(2)));
typedef __fp16 fp16x2 __attribute__((ext_vector_type(2)));
typedef float floatx4 __attribute__((ext_vector_type(4)));
typedef int int4v __attribute__((ext_vector_type(4)));

#define QMAX 127.0f

#define SLOT_WI 0
#define SLOT_WO 1
#define SLOT_XQ 2
#define SLOT_XK 3
#define SLOT_XV 4
#define SLOT_HD 5
#define SLOT_Y  6
#define SLOT_Q  7

__device__ __forceinline__ float slot_scale(const unsigned* slots, int slot, float premul) {
  if (slot < 0) return 1.0f;
  return fmaxf(__uint_as_float(slots[slot]) * premul / QMAX, 1e-8f);
}

__device__ __forceinline__ void gl2lds16(const void* gsrc, void* ldst) {
  __builtin_amdgcn_global_load_lds((__attribute__((address_space(1))) void*)gsrc,
                                   (__attribute__((address_space(3))) void*)ldst, 16, 0, 0);
}

__device__ __forceinline__ half2v pack2(float a, float b) {
  fp16x2 r = __builtin_amdgcn_cvt_pkrtz(a, b);
  return __builtin_bit_cast(half2v, r);
}

__global__ __launch_bounds__(64) void init_slots_k(unsigned* slots) {
  if (threadIdx.x < 16) slots[threadIdx.x] = 0u;
}

// Fused absmax of Wi (blocks < 768) and Wo (blocks >= 768).
__global__ __launch_bounds__(256) void absmax2_k(const float* __restrict__ Wi,
                                                 const float* __restrict__ Wo,
                                                 unsigned* __restrict__ slots) {
  __shared__ float red[256];
  int tid = threadIdx.x;
  const float4* x4;
  int n4, i0, stride, slot;
  if (blockIdx.x < 768) {
    x4 = (const float4*)Wi; n4 = 786432; i0 = blockIdx.x * 256 + tid;
    stride = 768 * 256; slot = SLOT_WI;
  } else {
    x4 = (const float4*)Wo; n4 = 262144; i0 = (blockIdx.x - 768) * 256 + tid;
    stride = 256 * 256; slot = SLOT_WO;
  }
  float lmax = 0.f;
  for (int i = i0; i < n4; i += stride) {
    float4 v = x4[i];
    lmax = fmaxf(lmax, fmaxf(fmaxf(fabsf(v.x), fabsf(v.y)), fmaxf(fabsf(v.z), fabsf(v.w))));
  }
  red[tid] = lmax; __syncthreads();
  for (int sh = 128; sh > 0; sh >>= 1) {
    if (tid < sh) red[tid] = fmaxf(red[tid], red[tid + sh]);
    __syncthreads();
  }
  if (tid == 0) atomicMax(&slots[slot], __float_as_uint(red[0]));
}

// Fused weight quant: Wi -> f16 codes (blocks < 768), Wo -> i8 codes.
__global__ __launch_bounds__(256) void quantw_k(const float* __restrict__ Wi,
                                                const float* __restrict__ Wo,
                                                f16* __restrict__ Wiq,
                                                char* __restrict__ Wo8,
                                                const unsigned* __restrict__ slots) {
  int tid = threadIdx.x;
  if (blockIdx.x < 768) {
    float s = slot_scale(slots, SLOT_WI, 1.0f);
    const float4* in4 = (const float4*)Wi;
    for (int i = blockIdx.x * 256 + tid; i < 786432; i += 768 * 256) {
      float4 v = in4[i];
      float xs[4] = {v.x, v.y, v.z, v.w};
      half4 o;
#pragma unroll
      for (int u = 0; u < 4; ++u) {
        float r = rintf(xs[u] / s);
        o[u] = (f16)fminf(fmaxf(r, -128.0f), 127.0f);
      }
      *(half4*)(Wiq + (size_t)i * 4) = o;
    }
  } else {
    float s = slot_scale(slots, SLOT_WO, 1.0f);
    const float4* in4 = (const float4*)Wo;
    for (int i = (blockIdx.x - 768) * 256 + tid; i < 262144; i += 256 * 256) {
      float4 v = in4[i];
      char4 o;
      o.x = (signed char)(int)fminf(fmaxf(rintf(v.x / s), -128.0f), 127.0f);
      o.y = (signed char)(int)fminf(fmaxf(rintf(v.y / s), -128.0f), 127.0f);
      o.z = (signed char)(int)fminf(fmaxf(rintf(v.z / s), -128.0f), 127.0f);
      o.w = (signed char)(int)fminf(fmaxf(rintf(v.w / s), -128.0f), 127.0f);
      *(char4*)(Wo8 + (size_t)i * 4) = o;
    }
  }
}

// fp32 -> fp32 fake-quant (n*s).
__global__ __launch_bounds__(256) void quantf_k(const float* __restrict__ in, float* __restrict__ out,
                                                int n4, unsigned* __restrict__ slots,
                                                int sSlot, float premul) {
  float s = slot_scale(slots, sSlot, premul);
  const float4* in4 = (const float4*)in;
  float4* out4 = (float4*)out;
  for (int i = blockIdx.x * 256 + threadIdx.x; i < n4; i += gridDim.x * 256) {
    float4 v = in4[i];
    float xs[4] = {v.x, v.y, v.z, v.w};
#pragma unroll
    for (int u = 0; u < 4; ++u) {
      float r = rintf((xs[u] * premul) / s);
      r = fminf(fmaxf(r, -128.0f), 127.0f);
      xs[u] = r * s;
    }
    out4[i] = make_float4(xs[0], xs[1], xs[2], xs[3]);
  }
}

// fp32 -> f16 integer codes. Optionally records absmax of quantized value.
__global__ __launch_bounds__(256) void quanti_k(const float* __restrict__ in, f16* __restrict__ out,
                                                int n4, unsigned* __restrict__ slots,
                                                int sSlot, int outAbsSlot) {
  __shared__ float red[256];
  float s = slot_scale(slots, sSlot, 1.0f);
  float lmax = 0.f;
  const float4* in4 = (const float4*)in;
  for (int i = blockIdx.x * 256 + threadIdx.x; i < n4; i += gridDim.x * 256) {
    float4 v = in4[i];
    float xs[4] = {v.x, v.y, v.z, v.w};
    half4 o;
#pragma unroll
    for (int u = 0; u < 4; ++u) {
      float r = rintf(xs[u] / s);
      r = fminf(fmaxf(r, -128.0f), 127.0f);
      o[u] = (f16)r;
      lmax = fmaxf(lmax, fabsf(r));
    }
    *(half4*)(out + (size_t)i * 4) = o;
  }
  if (outAbsSlot >= 0) {
    int tid = threadIdx.x;
    red[tid] = lmax; __syncthreads();
    for (int sh = 128; sh > 0; sh >>= 1) {
      if (tid < sh) red[tid] = fmaxf(red[tid], red[tid + sh]);
      __syncthreads();
    }
    if (tid == 0) atomicMax(&slots[outAbsSlot], __float_as_uint(red[0] * s));
  }
}

// fp32 -> i8 codes (for Hd -> Hint8).
__global__ __launch_bounds__(256) void quant8_k(const float* __restrict__ in, char* __restrict__ out,
                                                int n4, const unsigned* __restrict__ slots,
                                                int sSlot) {
  float s = slot_scale(slots, sSlot, 1.0f);
  const float4* in4 = (const float4*)in;
  for (int i = blockIdx.x * 256 + threadIdx.x; i < n4; i += gridDim.x * 256) {
    float4 v = in4[i];
    char4 o;
    o.x = (signed char)(int)fminf(fmaxf(rintf(v.x / s), -128.0f), 127.0f);
    o.y = (signed char)(int)fminf(fmaxf(rintf(v.y / s), -128.0f), 127.0f);
    o.z = (signed char)(int)fminf(fmaxf(rintf(v.z / s), -128.0f), 127.0f);
    o.w = (signed char)(int)fminf(fmaxf(rintf(v.w / s), -128.0f), 127.0f);
    *(char4*)(out + (size_t)i * 4) = o;
  }
}

// fp32 -> hi/lo f16 split.
__global__ __launch_bounds__(256) void split_k(const float* __restrict__ in,
                                               f16* __restrict__ hi, f16* __restrict__ lo, int n4) {
  const float4* in4 = (const float4*)in;
  for (int i = blockIdx.x * 256 + threadIdx.x; i < n4; i += gridDim.x * 256) {
    float4 v = in4[i];
    float xs[4] = {v.x, v.y, v.z, v.w};
    half4 h, l;
#pragma unroll
    for (int u = 0; u < 4; ++u) {
      f16 hv = (f16)xs[u];
      h[u] = hv;
      l[u] = (f16)(xs[u] - (float)hv);
    }
    *(half4*)(hi + (size_t)i * 4) = h;
    *(half4*)(lo + (size_t)i * 4) = l;
  }
}

// Fused V: quantize Xv -> codes, transpose per head, permute within each 64-k
// tile to the fused-S^T A-frag order: pos -> k = tp*32 + q*4 + (j<4? j : j+12),
// tp=pos>>5, q=(pos&31)>>3, j=pos&7.
__global__ __launch_bounds__(256) void quantv_t_k(const float* __restrict__ Xv,
                                                  f16* __restrict__ Vt,
                                                  const unsigned* __restrict__ slots) {
  __shared__ f16 T[64][68];
  int tid = threadIdx.x;
  int bh = blockIdx.y, b = bh >> 4, h = bh & 15;
  int k0 = blockIdx.x * 64;
  float s = slot_scale(slots, SLOT_XV, 1.0f);
#pragma unroll
  for (int it = 0; it < 4; ++it) {
    int idx = tid + it * 256;
    int row = idx >> 4, dseg = idx & 15;
    float4 v = *(const float4*)(Xv + ((size_t)(k0 + row) * 2 + b) * 1024 + h * 64 + dseg * 4);
    float xs[4] = {v.x, v.y, v.z, v.w};
    half4 o;
#pragma unroll
    for (int u = 0; u < 4; ++u) {
      float r = rintf(xs[u] / s);
      o[u] = (f16)fminf(fmaxf(r, -128.0f), 127.0f);
    }
    *(half4*)&T[row][dseg * 4] = o;
  }
  __syncthreads();
#pragma unroll
  for (int it = 0; it < 2; ++it) {
    int sdx = tid + it * 256;
    int d = sdx >> 3, j8 = sdx & 7;
    half8 o;
#pragma unroll
    for (int l = 0; l < 8; ++l) {
      int pos = j8 * 8 + l;
      int tp = pos >> 5, pq = (pos & 31) >> 3, jj = pos & 7;
      int k = tp * 32 + pq * 4 + ((jj < 4) ? jj : jj + 12);
      o[l] = T[k][d];
    }
    *(half8*)(Vt + ((size_t)bh * 64 + d) * 2048 + k0 + j8 * 8) = o;
  }
}

// f16 MFMA GEMM, BK=32 (R5/R7 structure). C = (A0+A1) @ B^T * sB + bias.
__global__ __launch_bounds__(256) void gemm_mfma_k(const f16* __restrict__ A0,
                                                   const f16* __restrict__ A1,
                                                   const f16* __restrict__ B,
                                                   const float* __restrict__ bias,
                                                   float* __restrict__ out,
                                                   unsigned* __restrict__ slots,
                                                   int slotB, int absSlot,
                                                   int K, int colLo, int colCount) {
  __shared__ f16 AsH[128 * 32];
  __shared__ f16 Bs[128 * 32];
  __shared__ f16 AsL[128 * 32];
  __shared__ float red[256];

  int tid = threadIdx.x;
  int lane = tid & 63, w = tid >> 6;
  int wm = w >> 1, wn = w & 1;
  int quad = lane >> 4, l15 = lane & 15;
  int m0 = blockIdx.y * 128, n0 = blockIdx.x * 128;

  int srow = lane >> 2;
  int sgr = (lane & 3) * 8;

  floatx4 acc[4][4];
#pragma unroll
  for (int i = 0; i < 4; ++i)
#pragma unroll
    for (int j = 0; j < 4; ++j) acc[i][j] = (floatx4){0.f, 0.f, 0.f, 0.f};

  for (int k0 = 0; k0 < K; k0 += 32) {
    __syncthreads();
#pragma unroll
    for (int t = 0; t < 2; ++t) {
      int r0 = (w * 2 + t) * 16;
      gl2lds16(A0 + (size_t)(m0 + r0 + srow) * K + k0 + sgr, &AsH[r0 * 32]);
      gl2lds16(B + (size_t)(n0 + r0 + srow) * K + k0 + sgr, &Bs[r0 * 32]);
      gl2lds16(A1 + (size_t)(m0 + r0 + srow) * K + k0 + sgr, &AsL[r0 * 32]);
    }
    __syncthreads();
    half8 ah[4], bfr[4], al[4];
#pragma unroll
    for (int i = 0; i < 4; ++i) ah[i] = *(half8*)&AsH[(wm * 64 + i * 16 + l15) * 32 + quad * 8];
#pragma unroll
    for (int j = 0; j < 4; ++j) bfr[j] = *(half8*)&Bs[(wn * 64 + j * 16 + l15) * 32 + quad * 8];
#pragma unroll
    for (int i = 0; i < 4; ++i) al[i] = *(half8*)&AsL[(wm * 64 + i * 16 + l15) * 32 + quad * 8];
#pragma unroll
    for (int i = 0; i < 4; ++i)
#pragma unroll
      for (int j = 0; j < 4; ++j) {
        acc[i][j] = __builtin_amdgcn_mfma_f32_16x16x32_f16(ah[i], bfr[j], acc[i][j], 0, 0, 0);
        acc[i][j] = __builtin_amdgcn_mfma_f32_16x16x32_f16(al[i], bfr[j], acc[i][j], 0, 0, 0);
      }
  }

  float sc = slot_scale(slots, slotB, 1.0f);
  float lmax = 0.f;
#pragma unroll
  for (int i = 0; i < 4; ++i) {
#pragma unroll
    for (int j = 0; j < 4; ++j) {
      int gn = n0 + wn * 64 + j * 16 + l15;
      float bv = bias[gn];
#pragma unroll
      for (int r = 0; r < 4; ++r) {
        int gm = m0 + wm * 64 + i * 16 + quad * 4 + r;
        float v = acc[i][j][r] * sc + bv;
        lmax = fmaxf(lmax, fabsf(v));
        if (gn >= colLo && gn < colLo + colCount)
          out[(size_t)gm * colCount + (gn - colLo)] = v;
      }
    }
  }
  red[tid] = lmax; __syncthreads();
  for (int sh = 128; sh > 0; sh >>= 1) {
    if (tid < sh) red[tid] = fmaxf(red[tid], red[tid + sh]);
    __syncthreads();
  }
  if (tid == 0) atomicMax(&slots[absSlot], __float_as_uint(red[0]));
}

// Exact i8 output GEMM: Y = (Hint8 @ Wo8^T) * (sH*sW) + bo.
__global__ __launch_bounds__(256) void gemm_i8out_k(const char* __restrict__ A8,
                                                    const char* __restrict__ B8,
                                                    const float* __restrict__ bias,
                                                    float* __restrict__ out,
                                                    unsigned* __restrict__ slots) {
  __shared__ char As8[128 * 64];
  __shared__ char Bs8[128 * 64];
  __shared__ float red[256];

  const int K = 1024;
  int tid = threadIdx.x;
  int lane = tid & 63, w = tid >> 6;
  int wm = w >> 1, wn = w & 1;
  int quad = lane >> 4, l15 = lane & 15;
  int m0 = blockIdx.y * 128, n0 = blockIdx.x * 128;

  int srow = lane >> 2;
  int sgr = (lane & 3) * 16;

  int4v acc[4][4];
#pragma unroll
  for (int i = 0; i < 4; ++i)
#pragma unroll
    for (int j = 0; j < 4; ++j) acc[i][j] = (int4v){0, 0, 0, 0};

  for (int k0 = 0; k0 < K; k0 += 64) {
    __syncthreads();
#pragma unroll
    for (int t = 0; t < 2; ++t) {
      int r0 = (w * 2 + t) * 16;
      int row = r0 + srow;
      gl2lds16(A8 + (size_t)(m0 + row) * K + k0 + sgr, &As8[r0 * 64]);
      gl2lds16(B8 + (size_t)(n0 + row) * K + k0 + sgr, &Bs8[r0 * 64]);
    }
    __syncthreads();
    int4v af[4], bf[4];
#pragma unroll
    for (int i = 0; i < 4; ++i)
      af[i] = *(const int4v*)&As8[(wm * 64 + i * 16 + l15) * 64 + quad * 16];
#pragma unroll
    for (int j = 0; j < 4; ++j)
      bf[j] = *(const int4v*)&Bs8[(wn * 64 + j * 16 + l15) * 64 + quad * 16];
#pragma unroll
    for (int i = 0; i < 4; ++i)
#pragma unroll
      for (int j = 0; j < 4; ++j)
        acc[i][j] = __builtin_amdgcn_mfma_i32_16x16x64_i8(af[i], bf[j], acc[i][j], 0, 0, 0);
  }

  float sc = slot_scale(slots, SLOT_HD, 1.0f) * slot_scale(slots, SLOT_WO, 1.0f);
  float lmax = 0.f;
#pragma unroll
  for (int i = 0; i < 4; ++i) {
#pragma unroll
    for (int j = 0; j < 4; ++j) {
      int gn = n0 + wn * 64 + j * 16 + l15;
      float bv = bias[gn];
#pragma unroll
      for (int r = 0; r < 4; ++r) {
        int gm = m0 + wm * 64 + i * 16 + quad * 4 + r;
        float v = (float)acc[i][j][r] * sc + bv;
        lmax = fmaxf(lmax, fabsf(v));
        out[(size_t)gm * 1024 + gn] = v;
      }
    }
  }
  red[tid] = lmax; __syncthreads();
  for (int sh = 128; sh > 0; sh >>= 1) {
    if (tid < sh) red[tid] = fmaxf(red[tid], red[tid + sh]);
    __syncthreads();
  }
  if (tid == 0) atomicMax(&slots[SLOT_Y], __float_as_uint(red[0]));
}

// Flash attention R10. 128 q-rows/block, 32 q-rows/wave (2x16 subs).
// S^T via mfma(kf, qf); two 16-k S^T blocks fused into one K=32 PV A-frag.
// P never touches LDS. Fixed-offset softmax. V pre-permuted globally.
__global__ __launch_bounds__(256) void attn_k(const f16* __restrict__ Qc,
                                              const f16* __restrict__ Kh,
                                              const f16* __restrict__ Vt,
                                              float* __restrict__ heads,
                                              unsigned* __restrict__ slots) {
  __shared__ f16 Ks[64 * 64];
  __shared__ f16 Vs[64][72];
  __shared__ float lred[4][2][16];
  __shared__ float red[256];

  int tid = threadIdx.x;
  int lane = tid & 63, w = tid >> 6;
  int quad = lane >> 4, l15 = lane & 15;
  int bh = blockIdx.y, b = bh >> 4, h = bh & 15;
  int q0 = blockIdx.x * 128;

  float s1 = slot_scale(slots, SLOT_XQ, 1.0f);
  float sq = slot_scale(slots, SLOT_Q, 0.125f);
  float sk = slot_scale(slots, SLOT_XK, 1.0f);
  float sv = slot_scale(slots, SLOT_XV, 1.0f);
  float cS = sq * sk * 1.44269504088896340736f;
  const float FOFF = 12.0f;  // cancels in P/l

  // Q fragments for both sub-tiles, remap fake_quant(Q/8) inline
  half8 qf[2][2];
#pragma unroll
  for (int s = 0; s < 2; ++s) {
    const f16* qrow = Qc + ((size_t)(q0 + w * 32 + s * 16 + l15) * 2 + b) * 1024 + h * 64;
    half8 qr0 = *(const half8*)(qrow + quad * 8);
    half8 qr1 = *(const half8*)(qrow + 32 + quad * 8);
#pragma unroll
    for (int u = 0; u < 8; ++u) {
      float x0 = ((float)qr0[u] * s1) * 0.125f;
      float x1 = ((float)qr1[u] * s1) * 0.125f;
      qf[s][0][u] = (f16)fminf(fmaxf(rintf(x0 / sq), -128.0f), 127.0f);
      qf[s][1][u] = (f16)fminf(fmaxf(rintf(x1 / sq), -128.0f), 127.0f);
    }
  }

  int ksrow = lane >> 3;
  int ksp = lane & 7;
  int vr0 = tid >> 3, vs0 = (tid & 7) * 8;

  floatx4 oacc[2][4];
#pragma unroll
  for (int s = 0; s < 2; ++s)
#pragma unroll
    for (int d = 0; d < 4; ++d) oacc[s][d] = (floatx4){0.f, 0.f, 0.f, 0.f};
  float lsum[2] = {0.f, 0.f};

  const f16* vbase = Vt + (size_t)bh * 131072;

  for (int kt = 0; kt < 2048; kt += 64) {
    __syncthreads();
#pragma unroll
    for (int t = 0; t < 2; ++t) {
      int r0 = (w * 2 + t) * 8;
      int row = r0 + ksrow;
      int g = ksp ^ (row & 7);
      gl2lds16(Kh + ((size_t)(kt + row) * 2 + b) * 1024 + h * 64 + g * 8, &Ks[r0 * 64]);
    }
    half8 va = *(const half8*)(vbase + (size_t)vr0 * 2048 + kt + vs0);
    half8 vb = *(const half8*)(vbase + (size_t)(vr0 + 32) * 2048 + kt + vs0);
    *(half8*)&Vs[vr0][vs0] = va;
    *(half8*)&Vs[vr0 + 32][vs0] = vb;
    __syncthreads();

    // S^T per 16-k block t; fuse pairs (t=2tp, 2tp+1) into K=32 A-frags
    half8 aph[2][2], apl[2][2];  // [s][tp]
#pragma unroll
    for (int t = 0; t < 4; ++t) {
      int row = t * 16 + l15;
      int g1 = quad ^ (row & 7);
      half8 kf0 = *(half8*)&Ks[row * 64 + g1 * 8];
      half8 kf1 = *(half8*)&Ks[row * 64 + (g1 ^ 4) * 8];
      int tp = t >> 1, hi = (t & 1) * 4;
#pragma unroll
      for (int s = 0; s < 2; ++s) {
        floatx4 sacc = (floatx4){0.f, 0.f, 0.f, 0.f};
        sacc = __builtin_amdgcn_mfma_f32_16x16x32_f16(kf0, qf[s][0], sacc, 0, 0, 0);
        sacc = __builtin_amdgcn_mfma_f32_16x16x32_f16(kf1, qf[s][1], sacc, 0, 0, 0);
        float p0 = __builtin_amdgcn_exp2f(fmaf(sacc[0], cS, -FOFF));
        float p1 = __builtin_amdgcn_exp2f(fmaf(sacc[1], cS, -FOFF));
        float p2 = __builtin_amdgcn_exp2f(fmaf(sacc[2], cS, -FOFF));
        float p3 = __builtin_amdgcn_exp2f(fmaf(sacc[3], cS, -FOFF));
        lsum[s] += (p0 + p1) + (p2 + p3);
        half2v h01 = pack2(p0, p1);
        half2v h23 = pack2(p2, p3);
        half2v l01 = pack2(p0 - (float)h01[0], p1 - (float)h01[1]);
        half2v l23 = pack2(p2 - (float)h23[0], p3 - (float)h23[1]);
        aph[s][tp][hi + 0] = h01[0]; aph[s][tp][hi + 1] = h01[1];
        aph[s][tp][hi + 2] = h23[0]; aph[s][tp][hi + 3] = h23[1];
        apl[s][tp][hi + 0] = l01[0]; apl[s][tp][hi + 1] = l01[1];
        apl[s][tp][hi + 2] = l23[0]; apl[s][tp][hi + 3] = l23[1];
      }
    }

    // PV: per d-block, B-frags are 2 contiguous b128 (tp=0,1); K=32 MFMAs
#pragma unroll
    for (int d = 0; d < 4; ++d) {
      const f16* vsrow = &Vs[d * 16 + l15][0];
      half8 b0 = *(const half8*)(vsrow + quad * 8);        // tp=0: pos quad*8..+7
      half8 b1 = *(const half8*)(vsrow + 32 + quad * 8);   // tp=1
#pragma unroll
      for (int s = 0; s < 2; ++s) {
        oacc[s][d] = __builtin_amdgcn_mfma_f32_16x16x32_f16(aph[s][0], b0, oacc[s][d], 0, 0, 0);
        oacc[s][d] = __builtin_amdgcn_mfma_f32_16x16x32_f16(apl[s][0], b0, oacc[s][d], 0, 0, 0);
        oacc[s][d] = __builtin_amdgcn_mfma_f32_16x16x32_f16(aph[s][1], b1, oacc[s][d], 0, 0, 0);
        oacc[s][d] = __builtin_amdgcn_mfma_f32_16x16x32_f16(apl[s][1], b1, oacc[s][d], 0, 0, 0);
      }
    }
  }

  // l: reduce across the 4 quads, broadcast via LDS (quad<->l15 remap)
#pragma unroll
  for (int s = 0; s < 2; ++s) {
    float l = lsum[s];
    l += __shfl_xor(l, 16);
    l += __shfl_xor(l, 32);
    lred[w][s][l15] = l;
  }
  float linv[2][4];
#pragma unroll
  for (int s = 0; s < 2; ++s)
#pragma unroll
    for (int r = 0; r < 4; ++r) linv[s][r] = sv / lred[w][s][quad * 4 + r];

  float lmax = 0.f;
#pragma unroll
  for (int s = 0; s < 2; ++s)
#pragma unroll
    for (int d = 0; d < 4; ++d)
#pragma unroll
      for (int r = 0; r < 4; ++r) {
        float hv = oacc[s][d][r] * linv[s][r];
        heads[((size_t)(q0 + w * 32 + s * 16 + quad * 4 + r) * 2 + b) * 1024 +
              h * 64 + d * 16 + l15] = hv;
        lmax = fmaxf(lmax, fabsf(hv));
      }
  red[tid] = lmax; __syncthreads();
  for (int sh = 128; sh > 0; sh >>= 1) {
    if (tid < sh) red[tid] = fmaxf(red[tid], red[tid + sh]);
    __syncthreads();
  }
  if (tid == 0) atomicMax(&slots[SLOT_HD], __float_as_uint(red[0]));
}

extern "C" void kernel_launch(void* const* d_in, const int* in_sizes, int n_in,
                              void* d_out, int out_size, void* d_ws, size_t ws_size,
                              hipStream_t stream) {
  (void)in_sizes; (void)n_in; (void)out_size; (void)ws_size;
  const float* query = (const float*)d_in[0];
  const float* key   = (const float*)d_in[1];
  const float* value = (const float*)d_in[2];
  const float* Wi    = (const float*)d_in[3];
  const float* bi    = (const float*)d_in[4];
  const float* Wo    = (const float*)d_in[5];
  const float* bo    = (const float*)d_in[6];
  float* out = (float*)d_out;

  char* p = (char*)d_ws;
  unsigned* slots = (unsigned*)p;            p += 1024;
  f16* Wiq  = (f16*)p;                       p += 3072 * 1024 * 2;
  char* Wo8 = (char*)p;                      p += 1024 * 1024;
  f16* Ahi  = (f16*)p;                       p += 4096 * 1024 * 2;
  f16* Alo  = (f16*)p;                       p += 4096 * 1024 * 2;
  float* Hd = (float*)Ahi;                   // alias (spans Ahi+Alo), after GEMM3
  float* Xq = (float*)p;                     p += 4096 * 1024 * 4;
  float* Y  = Xq;                            // alias: Xq dead after Qc made
  float* Xk = (float*)p;                     p += 4096 * 1024 * 4;
  f16* Qc   = (f16*)Xk;                      // alias: Xk dead after Kint (sequential)
  float* Xv = (float*)p;                     p += 4096 * 1024 * 4;
  char* Hint8 = (char*)Xv + 4096 * 1024 * 2; // alias: Xv dead after quantv_t
  f16* Kint = (f16*)p;                       p += 4096 * 1024 * 2;
  f16* Vt   = (f16*)p;                       p += 4096 * 1024 * 2;

  init_slots_k<<<1, 64, 0, stream>>>(slots);
  absmax2_k<<<1024, 256, 0, stream>>>(Wi, Wo, slots);
  quantw_k<<<1024, 256, 0, stream>>>(Wi, Wo, Wiq, Wo8, slots);

  dim3 g1(24, 32);  // N=3072, M=4096
  split_k<<<1024, 256, 0, stream>>>(query, Ahi, Alo, 1048576);
  gemm_mfma_k<<<g1, 256, 0, stream>>>(Ahi, Alo, Wiq, bi, Xq, slots, SLOT_WI, SLOT_XQ,
                                      1024, 0, 1024);
  split_k<<<1024, 256, 0, stream>>>(key, Ahi, Alo, 1048576);
  gemm_mfma_k<<<g1, 256, 0, stream>>>(Ahi, Alo, Wiq, bi, Xk, slots, SLOT_WI, SLOT_XK,
                                      1024, 1024, 1024);
  split_k<<<1024, 256, 0, stream>>>(value, Ahi, Alo, 1048576);
  gemm_mfma_k<<<g1, 256, 0, stream>>>(Ahi, Alo, Wiq, bi, Xv, slots, SLOT_WI, SLOT_XV,
                                      1024, 2048, 1024);

  quanti_k<<<1024, 256, 0, stream>>>(Xk, Kint, 1048576, slots, SLOT_XK, -1);
  quanti_k<<<1024, 256, 0, stream>>>(Xq, Qc, 1048576, slots, SLOT_XQ, SLOT_Q);

  dim3 gvt(32, 32);
  quantv_t_k<<<gvt, 256, 0, stream>>>(Xv, Vt, slots);

  dim3 ga(16, 32);
  attn_k<<<ga, 256, 0, stream>>>(Qc, Kint, Vt, Hd, slots);

  quant8_k<<<1024, 256, 0, stream>>>(Hd, Hint8, 1048576, slots, SLOT_HD);

  dim3 g2(8, 32);  // N=1024, M=4096
  gemm_i8out_k<<<g2, 256, 0, stream>>>(Hint8, Wo8, bo, Y, slots);

  quantf_k<<<1024, 256, 0, stream>>>(Y, out, 1048576, slots, SLOT_Y, 1.0f);
}